// Round 1
// baseline (208.447 us; speedup 1.0000x reference)
//
#include <hip/hip_runtime.h>
#include <hip/hip_bf16.h>
#include <math.h>

#define D 128
#define EPS 1e-7f

// One 64-lane wave per edge. Each lane holds float2 slice of z[src], z[dst], W.
// Wave-reduce dot(z_j, W) and ||z_i - z_j||^2 via xor-butterfly shuffles.
__global__ __launch_bounds__(256) void gravity_decoder_kernel(
    const float* __restrict__ z,      // [N, 128]
    const int*   __restrict__ ei,     // [2, E] (int32 per harness convention)
    const float* __restrict__ W,      // [128]
    const float* __restrict__ b,      // [1]
    float*       __restrict__ out,    // [4*E]: logits, prob, m_j, dist2
    int E)
{
    const int wave_in_block = threadIdx.x >> 6;
    const int lane          = threadIdx.x & 63;
    const int e = blockIdx.x * (blockDim.x >> 6) + wave_in_block;
    if (e >= E) return;

    const int src = ei[e];
    const int dst = ei[E + e];

    const float2* zi2 = (const float2*)(z + (size_t)src * D);
    const float2* zj2 = (const float2*)(z + (size_t)dst * D);
    const float2* w2  = (const float2*)W;

    const float2 a = zi2[lane];   // z_i slice
    const float2 c = zj2[lane];   // z_j slice
    const float2 w = w2[lane];

    float dot = c.x * w.x + c.y * w.y;        // partial z_j . W
    const float dx = a.x - c.x;
    const float dy = a.y - c.y;
    float d2 = dx * dx + dy * dy;             // partial ||z_i - z_j||^2

    // 64-lane butterfly reduction (wave = 64 on CDNA)
    #pragma unroll
    for (int off = 32; off > 0; off >>= 1) {
        dot += __shfl_xor(dot, off);
        d2  += __shfl_xor(d2,  off);
    }

    if (lane == 0) {
        const float mj     = dot + b[0];
        const float dist2  = d2 + EPS;
        const float logits = mj - logf(dist2);
        const float prob   = 1.0f / (1.0f + expf(-logits));
        out[e]         = logits;
        out[E + e]     = prob;
        out[2 * E + e] = mj;
        out[3 * E + e] = dist2;
    }
}

extern "C" void kernel_launch(void* const* d_in, const int* in_sizes, int n_in,
                              void* d_out, int out_size, void* d_ws, size_t ws_size,
                              hipStream_t stream)
{
    const float* z  = (const float*)d_in[0];
    const int*   ei = (const int*)d_in[1];
    const float* W  = (const float*)d_in[2];
    const float* b  = (const float*)d_in[3];
    float* out = (float*)d_out;

    const int E = in_sizes[1] / 2;   // edge_index is [2, E]

    const int waves_per_block = 4;   // 256 threads
    const int blocks = (E + waves_per_block - 1) / waves_per_block;
    gravity_decoder_kernel<<<blocks, 256, 0, stream>>>(z, ei, W, b, out, E);
}

// Round 2
// 163.881 us; speedup vs baseline: 1.2719x; 1.2719x over previous
//
#include <hip/hip_runtime.h>
#include <hip/hip_bf16.h>
#include <math.h>

#define D 128
#define EPS 1e-7f

// 32 lanes per edge, 2 edges per 64-lane wave. Each lane holds a float4
// slice of z[src], z[dst], W (32 lanes x 16B = 512B = full row).
// 5-step xor-butterfly (offsets 1..16 stay within each 32-lane half).
// Tail lanes 0 and 32 run the epilogue concurrently with fast
// v_log_f32 / v_exp_f32 intrinsics instead of libm.
__global__ __launch_bounds__(256) void gravity_decoder_kernel(
    const float* __restrict__ z,      // [N, 128]
    const int*   __restrict__ ei,     // [2, E] (int32 after harness cast)
    const float* __restrict__ W,      // [128]
    const float* __restrict__ b,      // [1]
    float*       __restrict__ out,    // [4*E]: logits, prob, m_j, dist2
    int E)
{
    const int wave_in_block = threadIdx.x >> 6;
    const int lane          = threadIdx.x & 63;
    const int half          = lane >> 5;        // 0 or 1
    const int sub           = lane & 31;        // lane within half

    const int e = (blockIdx.x * (blockDim.x >> 6) + wave_in_block) * 2 + half;
    if (e >= E) return;

    const int src = ei[e];          // 32 lanes same addr -> broadcast
    const int dst = ei[E + e];

    const float4* z4 = (const float4*)z;
    const float4 a = z4[(size_t)src * (D / 4) + sub];  // z_i slice
    const float4 c = z4[(size_t)dst * (D / 4) + sub];  // z_j slice
    const float4 w = ((const float4*)W)[sub];

    float dot = c.x * w.x + c.y * w.y + c.z * w.z + c.w * w.w;
    const float dx = a.x - c.x, dy = a.y - c.y, dz = a.z - c.z, dw = a.w - c.w;
    float d2 = dx * dx + dy * dy + dz * dz + dw * dw;

    // 5-step butterfly within each 32-lane half
    #pragma unroll
    for (int off = 16; off > 0; off >>= 1) {
        dot += __shfl_xor(dot, off);
        d2  += __shfl_xor(d2,  off);
    }

    if (sub == 0) {
        const float mj     = dot + b[0];
        const float dist2  = d2 + EPS;
        const float logits = mj - __logf(dist2);
        const float prob   = 1.0f / (1.0f + __expf(-logits));
        out[e]         = logits;
        out[E + e]     = prob;
        out[2 * E + e] = mj;
        out[3 * E + e] = dist2;
    }
}

extern "C" void kernel_launch(void* const* d_in, const int* in_sizes, int n_in,
                              void* d_out, int out_size, void* d_ws, size_t ws_size,
                              hipStream_t stream)
{
    const float* z  = (const float*)d_in[0];
    const int*   ei = (const int*)d_in[1];
    const float* W  = (const float*)d_in[2];
    const float* b  = (const float*)d_in[3];
    float* out = (float*)d_out;

    const int E = in_sizes[1] / 2;   // edge_index is [2, E]

    // 2 edges per wave, 4 waves per block -> 8 edges per block
    const int edges_per_block = 8;
    const int blocks = (E + edges_per_block - 1) / edges_per_block;
    gravity_decoder_kernel<<<blocks, 256, 0, stream>>>(z, ei, W, b, out, E);
}

// Round 3
// 140.159 us; speedup vs baseline: 1.4872x; 1.1692x over previous
//
#include <hip/hip_runtime.h>
#include <hip/hip_fp16.h>
#include <math.h>

#define D 128
#define EPS 1e-7f

typedef _Float16 half2v __attribute__((ext_vector_type(2)));
typedef unsigned int uint;

__device__ __forceinline__ float dot2acc(half2v a, half2v b, float c) {
#if __has_builtin(__builtin_amdgcn_fdot2)
    return __builtin_amdgcn_fdot2(a, b, c, false);   // v_dot2_f32_f16
#else
    return c + (float)a.x * (float)b.x + (float)a.y * (float)b.y;
#endif
}

// ---------------- Kernel 1: per-node precompute ----------------
// m[n] = z[n]·W + b   (exact f32, same math as reference)
// zh[n] = f16(z[n])   (halves gather bytes for the edge pass)
// 32 lanes per node, 2 nodes per 64-lane wave.
__global__ __launch_bounds__(256) void node_precompute_kernel(
    const float* __restrict__ z, const float* __restrict__ W,
    const float* __restrict__ b,
    _Float16* __restrict__ zh, float* __restrict__ m, int N)
{
    const int lane = threadIdx.x & 63;
    const int half = lane >> 5, sub = lane & 31;
    const int n = (blockIdx.x * (blockDim.x >> 6) + (threadIdx.x >> 6)) * 2 + half;
    if (n >= N) return;

    const float4 a = ((const float4*)(z + (size_t)n * D))[sub];
    const float4 w = ((const float4*)W)[sub];
    float dot = a.x * w.x + a.y * w.y + a.z * w.z + a.w * w.w;
    #pragma unroll
    for (int off = 16; off > 0; off >>= 1) dot += __shfl_xor(dot, off);

    half2v h0 = { (_Float16)a.x, (_Float16)a.y };
    half2v h1 = { (_Float16)a.z, (_Float16)a.w };
    uint2 pack;
    pack.x = __builtin_bit_cast(uint, h0);
    pack.y = __builtin_bit_cast(uint, h1);
    ((uint2*)(zh + (size_t)n * D))[sub] = pack;   // 8 B/lane, coalesced

    if (sub == 0) m[n] = dot + b[0];
}

// ---------------- Kernel 2: per-edge ----------------
// 16 lanes per edge, 4 edges per wave. Each lane: uint4 = 8 f16 of each row.
// d2 via packed f16 diff + v_dot2_f32_f16 (f32 accumulate).
__global__ __launch_bounds__(256) void edge_kernel(
    const _Float16* __restrict__ zh, const float* __restrict__ m,
    const int* __restrict__ ei, float* __restrict__ out, int E)
{
    const int lane = threadIdx.x & 63;
    const int q = lane >> 4, sub = lane & 15;
    const int e = (blockIdx.x * (blockDim.x >> 6) + (threadIdx.x >> 6)) * 4 + q;
    if (e >= E) return;

    const int src = ei[e];
    const int dst = ei[E + e];
    const float mj = m[dst];          // early, broadcast within quarter

    const uint4 ai = ((const uint4*)(zh + (size_t)src * D))[sub];
    const uint4 ci = ((const uint4*)(zh + (size_t)dst * D))[sub];

    float d2 = 0.f;
    {
        half2v d0 = __builtin_bit_cast(half2v, ai.x) - __builtin_bit_cast(half2v, ci.x);
        half2v d1 = __builtin_bit_cast(half2v, ai.y) - __builtin_bit_cast(half2v, ci.y);
        half2v d2v = __builtin_bit_cast(half2v, ai.z) - __builtin_bit_cast(half2v, ci.z);
        half2v d3 = __builtin_bit_cast(half2v, ai.w) - __builtin_bit_cast(half2v, ci.w);
        d2 = dot2acc(d0, d0, d2);
        d2 = dot2acc(d1, d1, d2);
        d2 = dot2acc(d2v, d2v, d2);
        d2 = dot2acc(d3, d3, d2);
    }

    #pragma unroll
    for (int off = 8; off > 0; off >>= 1) d2 += __shfl_xor(d2, off);

    if (sub == 0) {
        const float dist2  = d2 + EPS;
        const float logits = mj - __logf(dist2);
        const float prob   = 1.0f / (1.0f + __expf(-logits));
        out[e]         = logits;   // lanes 0,16,32,48 -> 16B contiguous
        out[E + e]     = prob;
        out[2 * E + e] = mj;
        out[3 * E + e] = dist2;
    }
}

// ---------------- Fallback (R2 kernel) if ws too small ----------------
__global__ __launch_bounds__(256) void gravity_decoder_fallback(
    const float* __restrict__ z, const int* __restrict__ ei,
    const float* __restrict__ W, const float* __restrict__ b,
    float* __restrict__ out, int E)
{
    const int lane = threadIdx.x & 63;
    const int half = lane >> 5, sub = lane & 31;
    const int e = (blockIdx.x * (blockDim.x >> 6) + (threadIdx.x >> 6)) * 2 + half;
    if (e >= E) return;
    const int src = ei[e], dst = ei[E + e];
    const float4* z4 = (const float4*)z;
    const float4 a = z4[(size_t)src * (D / 4) + sub];
    const float4 c = z4[(size_t)dst * (D / 4) + sub];
    const float4 w = ((const float4*)W)[sub];
    float dot = c.x * w.x + c.y * w.y + c.z * w.z + c.w * w.w;
    const float dx = a.x - c.x, dy = a.y - c.y, dz = a.z - c.z, dw = a.w - c.w;
    float d2 = dx * dx + dy * dy + dz * dz + dw * dw;
    #pragma unroll
    for (int off = 16; off > 0; off >>= 1) {
        dot += __shfl_xor(dot, off);
        d2  += __shfl_xor(d2,  off);
    }
    if (sub == 0) {
        const float mj = dot + b[0];
        const float dist2 = d2 + EPS;
        const float logits = mj - __logf(dist2);
        const float prob = 1.0f / (1.0f + __expf(-logits));
        out[e] = logits; out[E + e] = prob;
        out[2 * E + e] = mj; out[3 * E + e] = dist2;
    }
}

extern "C" void kernel_launch(void* const* d_in, const int* in_sizes, int n_in,
                              void* d_out, int out_size, void* d_ws, size_t ws_size,
                              hipStream_t stream)
{
    const float* z  = (const float*)d_in[0];
    const int*   ei = (const int*)d_in[1];
    const float* W  = (const float*)d_in[2];
    const float* b  = (const float*)d_in[3];
    float* out = (float*)d_out;

    const int E = in_sizes[1] / 2;   // edge_index is [2, E]
    const int N = in_sizes[0] / D;   // z is [N, 128]

    const size_t zh_bytes = (size_t)N * D * sizeof(_Float16);
    const size_t m_bytes  = (size_t)N * sizeof(float);

    if (ws_size >= zh_bytes + m_bytes) {
        _Float16* zh = (_Float16*)d_ws;
        float*    m  = (float*)((char*)d_ws + zh_bytes);

        const int nodes_per_block = 8;   // 2 nodes/wave x 4 waves
        node_precompute_kernel<<<(N + nodes_per_block - 1) / nodes_per_block,
                                 256, 0, stream>>>(z, W, b, zh, m, N);

        const int edges_per_block = 16;  // 4 edges/wave x 4 waves
        edge_kernel<<<(E + edges_per_block - 1) / edges_per_block,
                      256, 0, stream>>>(zh, m, ei, out, E);
    } else {
        const int edges_per_block = 8;
        gravity_decoder_fallback<<<(E + edges_per_block - 1) / edges_per_block,
                                   256, 0, stream>>>(z, ei, W, b, out, E);
    }
}

// Round 4
// 134.078 us; speedup vs baseline: 1.5547x; 1.0454x over previous
//
#include <hip/hip_runtime.h>
#include <hip/hip_fp16.h>
#include <math.h>

#define D 128
#define EPS 1e-7f

typedef _Float16 half2v __attribute__((ext_vector_type(2)));
typedef unsigned int uint;

__device__ __forceinline__ float dot2acc(half2v a, half2v b, float c) {
#if __has_builtin(__builtin_amdgcn_fdot2)
    return __builtin_amdgcn_fdot2(a, b, c, false);   // v_dot2_f32_f16
#else
    return c + (float)a.x * (float)b.x + (float)a.y * (float)b.y;
#endif
}

__device__ __forceinline__ float d2_of(uint x, uint y, float acc) {
    half2v d = __builtin_bit_cast(half2v, x) - __builtin_bit_cast(half2v, y);
    return dot2acc(d, d, acc);
}

// ---------------- Kernel 1: per-node precompute ----------------
// m[n] = z[n]·W + b (exact f32); zh[n] = f16(z[n]).
__global__ __launch_bounds__(256) void node_precompute_kernel(
    const float* __restrict__ z, const float* __restrict__ W,
    const float* __restrict__ b,
    _Float16* __restrict__ zh, float* __restrict__ m, int N)
{
    const int lane = threadIdx.x & 63;
    const int half = lane >> 5, sub = lane & 31;
    const int n = (blockIdx.x * (blockDim.x >> 6) + (threadIdx.x >> 6)) * 2 + half;
    if (n >= N) return;

    const float4 a = ((const float4*)(z + (size_t)n * D))[sub];
    const float4 w = ((const float4*)W)[sub];
    float dot = a.x * w.x + a.y * w.y + a.z * w.z + a.w * w.w;
    #pragma unroll
    for (int off = 16; off > 0; off >>= 1) dot += __shfl_xor(dot, off);

    half2v h0 = { (_Float16)a.x, (_Float16)a.y };
    half2v h1 = { (_Float16)a.z, (_Float16)a.w };
    uint2 pack;
    pack.x = __builtin_bit_cast(uint, h0);
    pack.y = __builtin_bit_cast(uint, h1);
    ((uint2*)(zh + (size_t)n * D))[sub] = pack;

    if (sub == 0) m[n] = dot + b[0];
}

// ---------------- Kernel 2: per-edge ----------------
// 8 lanes per edge, 8 edges per wave. Each lane loads 32 B (2x uint4 =
// 16 f16) of each row -> 4 outstanding 16B gathers per lane (high MLP).
// 3-step xor-butterfly within each 8-lane group.
__global__ __launch_bounds__(256) void edge_kernel(
    const _Float16* __restrict__ zh, const float* __restrict__ m,
    const int* __restrict__ ei, float* __restrict__ out, int E)
{
    const int lane = threadIdx.x & 63;
    const int sub = lane & 7;                        // lane within group
    const int e = (blockIdx.x * (blockDim.x >> 6) + (threadIdx.x >> 6)) * 8
                  + (lane >> 3);
    if (e >= E) return;

    const int src = ei[e];
    const int dst = ei[E + e];
    const float mj = m[dst];                         // L2-resident (400 KB)

    const uint4* ri = (const uint4*)(zh + (size_t)src * D) + sub * 2;
    const uint4* rj = (const uint4*)(zh + (size_t)dst * D) + sub * 2;
    const uint4 a0 = ri[0];
    const uint4 a1 = ri[1];
    const uint4 c0 = rj[0];
    const uint4 c1 = rj[1];

    float d2 = 0.f;
    d2 = d2_of(a0.x, c0.x, d2);
    d2 = d2_of(a0.y, c0.y, d2);
    d2 = d2_of(a0.z, c0.z, d2);
    d2 = d2_of(a0.w, c0.w, d2);
    d2 = d2_of(a1.x, c1.x, d2);
    d2 = d2_of(a1.y, c1.y, d2);
    d2 = d2_of(a1.z, c1.z, d2);
    d2 = d2_of(a1.w, c1.w, d2);

    #pragma unroll
    for (int off = 4; off > 0; off >>= 1) d2 += __shfl_xor(d2, off);

    if (sub == 0) {
        const float dist2  = d2 + EPS;
        const float logits = mj - __logf(dist2);
        const float prob   = 1.0f / (1.0f + __expf(-logits));
        out[e]         = logits;    // 8 edges/wave -> 32B contiguous per array
        out[E + e]     = prob;
        out[2 * E + e] = mj;
        out[3 * E + e] = dist2;
    }
}

// ---------------- Fallback if ws too small ----------------
__global__ __launch_bounds__(256) void gravity_decoder_fallback(
    const float* __restrict__ z, const int* __restrict__ ei,
    const float* __restrict__ W, const float* __restrict__ b,
    float* __restrict__ out, int E)
{
    const int lane = threadIdx.x & 63;
    const int half = lane >> 5, sub = lane & 31;
    const int e = (blockIdx.x * (blockDim.x >> 6) + (threadIdx.x >> 6)) * 2 + half;
    if (e >= E) return;
    const int src = ei[e], dst = ei[E + e];
    const float4* z4 = (const float4*)z;
    const float4 a = z4[(size_t)src * (D / 4) + sub];
    const float4 c = z4[(size_t)dst * (D / 4) + sub];
    const float4 w = ((const float4*)W)[sub];
    float dot = c.x * w.x + c.y * w.y + c.z * w.z + c.w * w.w;
    const float dx = a.x - c.x, dy = a.y - c.y, dz = a.z - c.z, dw = a.w - c.w;
    float d2 = dx * dx + dy * dy + dz * dz + dw * dw;
    #pragma unroll
    for (int off = 16; off > 0; off >>= 1) {
        dot += __shfl_xor(dot, off);
        d2  += __shfl_xor(d2,  off);
    }
    if (sub == 0) {
        const float mj = dot + b[0];
        const float dist2 = d2 + EPS;
        const float logits = mj - __logf(dist2);
        const float prob = 1.0f / (1.0f + __expf(-logits));
        out[e] = logits; out[E + e] = prob;
        out[2 * E + e] = mj; out[3 * E + e] = dist2;
    }
}

extern "C" void kernel_launch(void* const* d_in, const int* in_sizes, int n_in,
                              void* d_out, int out_size, void* d_ws, size_t ws_size,
                              hipStream_t stream)
{
    const float* z  = (const float*)d_in[0];
    const int*   ei = (const int*)d_in[1];
    const float* W  = (const float*)d_in[2];
    const float* b  = (const float*)d_in[3];
    float* out = (float*)d_out;

    const int E = in_sizes[1] / 2;   // edge_index is [2, E]
    const int N = in_sizes[0] / D;   // z is [N, 128]

    const size_t zh_bytes = (size_t)N * D * sizeof(_Float16);
    const size_t m_bytes  = (size_t)N * sizeof(float);

    if (ws_size >= zh_bytes + m_bytes) {
        _Float16* zh = (_Float16*)d_ws;
        float*    m  = (float*)((char*)d_ws + zh_bytes);

        const int nodes_per_block = 8;   // 2 nodes/wave x 4 waves
        node_precompute_kernel<<<(N + nodes_per_block - 1) / nodes_per_block,
                                 256, 0, stream>>>(z, W, b, zh, m, N);

        const int edges_per_block = 32;  // 8 edges/wave x 4 waves
        edge_kernel<<<(E + edges_per_block - 1) / edges_per_block,
                      256, 0, stream>>>(zh, m, ei, out, E);
    } else {
        const int edges_per_block = 8;
        gravity_decoder_fallback<<<(E + edges_per_block - 1) / edges_per_block,
                                   256, 0, stream>>>(z, ei, W, b, out, E);
    }
}

// Round 5
// 119.898 us; speedup vs baseline: 1.7385x; 1.1183x over previous
//
#include <hip/hip_runtime.h>
#include <hip/hip_fp16.h>
#include <math.h>

#define D 128
#define EPS 1e-7f

typedef unsigned int uint;

__device__ __forceinline__ int sdot4(int a, int b, int c) {
#if __has_builtin(__builtin_amdgcn_sdot4)
    return __builtin_amdgcn_sdot4(a, b, c, false);   // v_dot4_i32_i8
#else
    int r = c;
    #pragma unroll
    for (int i = 0; i < 4; ++i) {
        int av = (a << (24 - 8 * i)) >> 24;
        int bv = (b << (24 - 8 * i)) >> 24;
        r += av * bv;
    }
    return r;
#endif
}

// ---------------- Kernel 1: per-node precompute ----------------
// m[n] = z[n]·W + b (exact f32, matches reference math).
// q[n] = round(z[n]/s_n) int8, s_n = rowmax/127 (per-row scale).
// meta[n] = {s_n, bitcast(S_n=Σq²), m_n, 0} as float4.
// 32 lanes per node, 2 nodes per wave.
__global__ __launch_bounds__(256) void node_precompute_kernel(
    const float* __restrict__ z, const float* __restrict__ W,
    const float* __restrict__ b,
    uint* __restrict__ zq,        // [N, 32] dwords (128 i8 per row)
    float4* __restrict__ meta, int N)
{
    const int lane = threadIdx.x & 63;
    const int half = lane >> 5, sub = lane & 31;
    const int n = (blockIdx.x * (blockDim.x >> 6) + (threadIdx.x >> 6)) * 2 + half;
    if (n >= N) return;

    const float4 a = ((const float4*)(z + (size_t)n * D))[sub];
    const float4 w = ((const float4*)W)[sub];

    float dot = a.x * w.x + a.y * w.y + a.z * w.z + a.w * w.w;
    float amax = fmaxf(fmaxf(fabsf(a.x), fabsf(a.y)), fmaxf(fabsf(a.z), fabsf(a.w)));
    #pragma unroll
    for (int off = 16; off > 0; off >>= 1) {
        dot  += __shfl_xor(dot, off);
        amax  = fmaxf(amax, __shfl_xor(amax, off));
    }

    const float s   = amax * (1.0f / 127.0f);
    const float inv = 127.0f / fmaxf(amax, 1e-30f);

    const int q0 = (int)rintf(fminf(fmaxf(a.x * inv, -127.f), 127.f));
    const int q1 = (int)rintf(fminf(fmaxf(a.y * inv, -127.f), 127.f));
    const int q2 = (int)rintf(fminf(fmaxf(a.z * inv, -127.f), 127.f));
    const int q3 = (int)rintf(fminf(fmaxf(a.w * inv, -127.f), 127.f));
    const uint pack = (uint)(q0 & 255) | ((uint)(q1 & 255) << 8)
                    | ((uint)(q2 & 255) << 16) | ((uint)q3 << 24);
    zq[(size_t)n * 32 + sub] = pack;

    int S = sdot4((int)pack, (int)pack, 0);
    #pragma unroll
    for (int off = 16; off > 0; off >>= 1) S += __shfl_xor(S, off);

    if (sub == 0) {
        float4 mt;
        mt.x = s;
        mt.y = __builtin_bit_cast(float, S);
        mt.z = dot + b[0];
        mt.w = 0.f;
        meta[n] = mt;
    }
}

// ---------------- Kernel 2: per-edge ----------------
// 8 lanes per edge, 8 edges per wave. Each lane: one uint4 (16 i8) of each
// row -> full 128 B row per 8-lane group. Cross-dot via exact i32 sdot4.
// dist2 = si²·Si + sj²·Sj − 2·si·sj·dot  (==0 exactly when src==dst).
__global__ __launch_bounds__(256) void edge_kernel(
    const uint* __restrict__ zq, const float4* __restrict__ meta,
    const int* __restrict__ ei, float* __restrict__ out, int E)
{
    const int lane = threadIdx.x & 63;
    const int sub = lane & 7;
    const int e = (blockIdx.x * (blockDim.x >> 6) + (threadIdx.x >> 6)) * 8
                  + (lane >> 3);
    if (e >= E) return;

    const int src = ei[e];
    const int dst = ei[E + e];

    const float4 Mi = meta[src];     // 1.6 MB table, L2-resident
    const float4 Mj = meta[dst];

    const uint4 ai = ((const uint4*)(zq + (size_t)src * 32))[sub];
    const uint4 ci = ((const uint4*)(zq + (size_t)dst * 32))[sub];

    int dot = sdot4((int)ai.x, (int)ci.x, 0);
    dot = sdot4((int)ai.y, (int)ci.y, dot);
    dot = sdot4((int)ai.z, (int)ci.z, dot);
    dot = sdot4((int)ai.w, (int)ci.w, dot);

    #pragma unroll
    for (int off = 4; off > 0; off >>= 1) dot += __shfl_xor(dot, off);

    if (sub == 0) {
        const float si = Mi.x, sj = Mj.x;
        const int   Si = __builtin_bit_cast(int, Mi.y);
        const int   Sj = __builtin_bit_cast(int, Mj.y);
        const float mj = Mj.z;

        const float u = (si * si) * (float)Si;
        const float v = (sj * sj) * (float)Sj;
        const float wc = (si * sj) * (float)dot;
        const float dist2 = fmaxf(u + v - wc - wc, 0.0f) + EPS;

        const float logits = mj - __logf(dist2);
        const float prob   = 1.0f / (1.0f + __expf(-logits));
        out[e]         = logits;
        out[E + e]     = prob;
        out[2 * E + e] = mj;
        out[3 * E + e] = dist2;
    }
}

// ---------------- Fallback if ws too small ----------------
__global__ __launch_bounds__(256) void gravity_decoder_fallback(
    const float* __restrict__ z, const int* __restrict__ ei,
    const float* __restrict__ W, const float* __restrict__ b,
    float* __restrict__ out, int E)
{
    const int lane = threadIdx.x & 63;
    const int half = lane >> 5, sub = lane & 31;
    const int e = (blockIdx.x * (blockDim.x >> 6) + (threadIdx.x >> 6)) * 2 + half;
    if (e >= E) return;
    const int src = ei[e], dst = ei[E + e];
    const float4* z4 = (const float4*)z;
    const float4 a = z4[(size_t)src * (D / 4) + sub];
    const float4 c = z4[(size_t)dst * (D / 4) + sub];
    const float4 w = ((const float4*)W)[sub];
    float dot = c.x * w.x + c.y * w.y + c.z * w.z + c.w * w.w;
    const float dx = a.x - c.x, dy = a.y - c.y, dz = a.z - c.z, dw = a.w - c.w;
    float d2 = dx * dx + dy * dy + dz * dz + dw * dw;
    #pragma unroll
    for (int off = 16; off > 0; off >>= 1) {
        dot += __shfl_xor(dot, off);
        d2  += __shfl_xor(d2,  off);
    }
    if (sub == 0) {
        const float mj = dot + b[0];
        const float dist2 = d2 + EPS;
        const float logits = mj - __logf(dist2);
        const float prob = 1.0f / (1.0f + __expf(-logits));
        out[e] = logits; out[E + e] = prob;
        out[2 * E + e] = mj; out[3 * E + e] = dist2;
    }
}

extern "C" void kernel_launch(void* const* d_in, const int* in_sizes, int n_in,
                              void* d_out, int out_size, void* d_ws, size_t ws_size,
                              hipStream_t stream)
{
    const float* z  = (const float*)d_in[0];
    const int*   ei = (const int*)d_in[1];
    const float* W  = (const float*)d_in[2];
    const float* b  = (const float*)d_in[3];
    float* out = (float*)d_out;

    const int E = in_sizes[1] / 2;   // edge_index is [2, E]
    const int N = in_sizes[0] / D;   // z is [N, 128]

    const size_t zq_bytes   = (size_t)N * D;              // i8 rows
    const size_t meta_bytes = (size_t)N * sizeof(float4);

    if (ws_size >= zq_bytes + meta_bytes) {
        uint*   zq   = (uint*)d_ws;
        float4* meta = (float4*)((char*)d_ws + zq_bytes);

        const int nodes_per_block = 8;   // 2 nodes/wave x 4 waves
        node_precompute_kernel<<<(N + nodes_per_block - 1) / nodes_per_block,
                                 256, 0, stream>>>(z, W, b, zq, meta, N);

        const int edges_per_block = 32;  // 8 edges/wave x 4 waves
        edge_kernel<<<(E + edges_per_block - 1) / edges_per_block,
                      256, 0, stream>>>(zq, meta, ei, out, E);
    } else {
        const int edges_per_block = 8;
        gravity_decoder_fallback<<<(E + edges_per_block - 1) / edges_per_block,
                                   256, 0, stream>>>(z, ei, W, b, out, E);
    }
}

// Round 7
// 118.343 us; speedup vs baseline: 1.7614x; 1.0131x over previous
//
#include <hip/hip_runtime.h>
#include <math.h>

#define D 128
#define EPS 1e-7f

typedef unsigned int uint;

__device__ __forceinline__ int sdot4(int a, int b, int c) {
#if __has_builtin(__builtin_amdgcn_sdot4)
    return __builtin_amdgcn_sdot4(a, b, c, false);   // v_dot4_i32_i8
#else
    int r = c;
    #pragma unroll
    for (int i = 0; i < 4; ++i) {
        int av = (a << (24 - 8 * i)) >> 24;
        int bv = (b << (24 - 8 * i)) >> 24;
        r += av * bv;
    }
    return r;
#endif
}

// ---------------- Kernel 1: per-node precompute ----------------
// m[n] = z[n]·W + b (exact f32, matches reference math).
// q[n] = round(z[n]/s_n) int8, s_n = rowmax/127; row = 32 dwords (128 B).
// meta[n] = {s_n, nrm_n = s_n^2·Σq², m_n, 0} as float4.
// 32 lanes per node, 2 nodes per wave.
__global__ __launch_bounds__(256) void node_precompute_kernel(
    const float* __restrict__ z, const float* __restrict__ W,
    const float* __restrict__ b,
    uint* __restrict__ zq,        // [N, 32] dwords (128 i8 per row)
    float4* __restrict__ meta, int N)
{
    const int lane = threadIdx.x & 63;
    const int half = lane >> 5, sub = lane & 31;
    const int n = (blockIdx.x * (blockDim.x >> 6) + (threadIdx.x >> 6)) * 2 + half;
    if (n >= N) return;

    const float4 a = ((const float4*)(z + (size_t)n * D))[sub];
    const float4 w = ((const float4*)W)[sub];

    float dot = a.x * w.x + a.y * w.y + a.z * w.z + a.w * w.w;
    float amax = fmaxf(fmaxf(fabsf(a.x), fabsf(a.y)), fmaxf(fabsf(a.z), fabsf(a.w)));
    #pragma unroll
    for (int off = 16; off > 0; off >>= 1) {
        dot  += __shfl_xor(dot, off);
        amax  = fmaxf(amax, __shfl_xor(amax, off));
    }

    const float s   = amax * (1.0f / 127.0f);
    const float inv = 127.0f / fmaxf(amax, 1e-30f);

    const int q0 = (int)rintf(fminf(fmaxf(a.x * inv, -127.f), 127.f));
    const int q1 = (int)rintf(fminf(fmaxf(a.y * inv, -127.f), 127.f));
    const int q2 = (int)rintf(fminf(fmaxf(a.z * inv, -127.f), 127.f));
    const int q3 = (int)rintf(fminf(fmaxf(a.w * inv, -127.f), 127.f));
    const uint pack = (uint)(q0 & 255) | ((uint)(q1 & 255) << 8)
                    | ((uint)(q2 & 255) << 16) | ((uint)q3 << 24);
    zq[(size_t)n * 32 + sub] = pack;

    int S = sdot4((int)pack, (int)pack, 0);
    #pragma unroll
    for (int off = 16; off > 0; off >>= 1) S += __shfl_xor(S, off);

    if (sub == 0) {
        float4 mt;
        mt.x = s;
        mt.y = (s * s) * (float)S;   // nrm; edge-side wc uses identical expr
        mt.z = dot + b[0];
        mt.w = 0.f;
        meta[n] = mt;
    }
}

// ---------------- Kernel 2: per-edge ----------------
// 4 lanes per edge, 16 edges per wave. Lane sub loads row[sub] and
// row[sub+4] (uint4 each) -> each load instr covers one 64 B half-row
// per 4-lane group. Cross-dot exact i32 via sdot4; 2-step butterfly.
// dist2 = nrm_i + nrm_j − 2·si·sj·dot  (==0 exactly when src==dst).
__global__ __launch_bounds__(256) void edge_kernel(
    const uint* __restrict__ zq, const float4* __restrict__ meta,
    const int* __restrict__ ei, float* __restrict__ out, int E)
{
    const int lane = threadIdx.x & 63;
    const int sub = lane & 3;
    const int e = (blockIdx.x * (blockDim.x >> 6) + (threadIdx.x >> 6)) * 16
                  + (lane >> 2);
    if (e >= E) return;

    const int src = ei[e];
    const int dst = ei[E + e];

    const float4 Mi = meta[src];     // 1.6 MB table, mostly L2-resident
    const float4 Mj = meta[dst];

    const uint4* ri = (const uint4*)(zq + (size_t)src * 32);
    const uint4* rj = (const uint4*)(zq + (size_t)dst * 32);
    const uint4 a0 = ri[sub];
    const uint4 a1 = ri[sub + 4];
    const uint4 c0 = rj[sub];
    const uint4 c1 = rj[sub + 4];

    int dot = sdot4((int)a0.x, (int)c0.x, 0);
    dot = sdot4((int)a0.y, (int)c0.y, dot);
    dot = sdot4((int)a0.z, (int)c0.z, dot);
    dot = sdot4((int)a0.w, (int)c0.w, dot);
    dot = sdot4((int)a1.x, (int)c1.x, dot);
    dot = sdot4((int)a1.y, (int)c1.y, dot);
    dot = sdot4((int)a1.z, (int)c1.z, dot);
    dot = sdot4((int)a1.w, (int)c1.w, dot);

    dot += __shfl_xor(dot, 1);
    dot += __shfl_xor(dot, 2);

    if (sub == 0) {
        const float wc = (Mi.x * Mj.x) * (float)dot;
        const float dist2 = fmaxf(Mi.y + Mj.y - wc - wc, 0.0f) + EPS;
        const float logits = Mj.z - __logf(dist2);
        const float prob   = 1.0f / (1.0f + __expf(-logits));
        out[e]         = logits;   // 16 edges/wave -> 64 B contiguous/array
        out[E + e]     = prob;
        out[2 * E + e] = Mj.z;
        out[3 * E + e] = dist2;
    }
}

// ---------------- Fallback if ws too small ----------------
__global__ __launch_bounds__(256) void gravity_decoder_fallback(
    const float* __restrict__ z, const int* __restrict__ ei,
    const float* __restrict__ W, const float* __restrict__ b,
    float* __restrict__ out, int E)
{
    const int lane = threadIdx.x & 63;
    const int half = lane >> 5, sub = lane & 31;
    const int e = (blockIdx.x * (blockDim.x >> 6) + (threadIdx.x >> 6)) * 2 + half;
    if (e >= E) return;
    const int src = ei[e], dst = ei[E + e];
    const float4* z4 = (const float4*)z;
    const float4 a = z4[(size_t)src * (D / 4) + sub];
    const float4 c = z4[(size_t)dst * (D / 4) + sub];
    const float4 w = ((const float4*)W)[sub];
    float dot = c.x * w.x + c.y * w.y + c.z * w.z + c.w * w.w;
    const float dx = a.x - c.x, dy = a.y - c.y, dz = a.z - c.z, dw = a.w - c.w;
    float d2 = dx * dx + dy * dy + dz * dz + dw * dw;
    #pragma unroll
    for (int off = 16; off > 0; off >>= 1) {
        dot += __shfl_xor(dot, off);
        d2  += __shfl_xor(d2,  off);
    }
    if (sub == 0) {
        const float mj = dot + b[0];
        const float dist2 = d2 + EPS;
        const float logits = mj - __logf(dist2);
        const float prob = 1.0f / (1.0f + __expf(-logits));
        out[e] = logits; out[E + e] = prob;
        out[2 * E + e] = mj; out[3 * E + e] = dist2;
    }
}

extern "C" void kernel_launch(void* const* d_in, const int* in_sizes, int n_in,
                              void* d_out, int out_size, void* d_ws, size_t ws_size,
                              hipStream_t stream)
{
    const float* z  = (const float*)d_in[0];
    const int*   ei = (const int*)d_in[1];
    const float* W  = (const float*)d_in[2];
    const float* b  = (const float*)d_in[3];
    float* out = (float*)d_out;

    const int E = in_sizes[1] / 2;   // edge_index is [2, E]
    const int N = in_sizes[0] / D;   // z is [N, 128]

    const size_t zq_bytes   = (size_t)N * D;              // i8 rows, 128 B
    const size_t meta_bytes = (size_t)N * sizeof(float4);

    if (ws_size >= zq_bytes + meta_bytes) {
        uint*   zq   = (uint*)d_ws;
        float4* meta = (float4*)((char*)d_ws + zq_bytes);

        const int nodes_per_block = 8;   // 2 nodes/wave x 4 waves
        node_precompute_kernel<<<(N + nodes_per_block - 1) / nodes_per_block,
                                 256, 0, stream>>>(z, W, b, zq, meta, N);

        const int edges_per_block = 64;  // 16 edges/wave x 4 waves
        edge_kernel<<<(E + edges_per_block - 1) / edges_per_block,
                      256, 0, stream>>>(zq, meta, ei, out, E);
    } else {
        const int edges_per_block = 8;
        gravity_decoder_fallback<<<(E + edges_per_block - 1) / edges_per_block,
                                   256, 0, stream>>>(z, ei, W, b, out, E);
    }
}